// Round 1
// baseline (503.167 us; speedup 1.0000x reference)
//
#include <hip/hip_runtime.h>
#include <hip/hip_bf16.h>

// Problem constants
#define NNEUR 8192
#define NCONV 64
#define LYC   36
#define LXC   36
#define BATCH 256
#define KRAW  1296   // 36*36
#define KPAD  1344   // 21*64
#define KITER 21     // KPAD/64
#define MROWS 16384  // BATCH*NCONV
#define BM 256
#define BN 256
#define BK 64
// One K-tile image per operand per iter: 2048 chunks of 16B = 32 KB.
#define A_IT_H   16384                 // halfs per (tile, it)
#define A_TILE_H (KITER * A_IT_H)      // 344064 halfs = 672 KB
#define B_TILE_H (KITER * A_IT_H)      // same (256-row n-tiles now)

typedef __attribute__((ext_vector_type(8))) _Float16 half8;
typedef __attribute__((ext_vector_type(4))) float f32x4;
typedef __attribute__((ext_vector_type(16))) float f32x16;

__device__ __forceinline__ void async_copy16(const void* g, void* l) {
  __builtin_amdgcn_global_load_lds(
      (const __attribute__((address_space(1))) void*)g,
      (__attribute__((address_space(3))) void*)l, 16, 0, 0);
}

// Prep: emit A (conv->f16) and B (Wy*Wx*256->f16) in the GEMM's staged
// LDS-image order with the bank-XOR swizzle baked in. Image layout per
// (tile, it): halfs offset (r*8 + s)*8 holds source chunk c = (s - r)&7 of
// row r (r = row within tile, chunk = 16B of the BK=64 row).
// grid: x = 0..167 -> A (it = x>>3, i = x&7, mtile = y);
//       x = 168..251 -> B (x'=x-168, it = x'>>2, i4 = x'&3,
//                          ntile = y>>1, row-half = y&1).
__global__ __launch_bounds__(256) void prep_kernel(
    const float* __restrict__ conv, const float* __restrict__ Wy,
    const float* __restrict__ Wx, _Float16* __restrict__ A,
    _Float16* __restrict__ B) {
  const int t = threadIdx.x;
  const int bx = blockIdx.x;
  const int slot = t & 7;
  half8 h;
  if (bx < 168) {  // A part (unchanged image)
    const int tile = blockIdx.y;
    const int it = bx >> 3, i = bx & 7;
    const int r = (t >> 3) + 32 * i;                 // row in tile, 0..255
    const int c = (slot - r) & 7;                    // source chunk
    const int k0 = it * 64 + c * 8;
    const int grow = tile * BM + r;
    if (k0 < KRAW) {
      const float* s = conv + (size_t)grow * KRAW + k0;
#pragma unroll
      for (int e = 0; e < 8; e++) h[e] = (_Float16)s[e];
    } else {
#pragma unroll
      for (int e = 0; e < 8; e++) h[e] = (_Float16)0.f;
    }
    *(half8*)(A + (size_t)tile * A_TILE_H + ((size_t)bx * 256 + t) * 8) = h;
  } else {  // B part: 256-row n-tiles, 32 tiles
    const int bxp = bx - 168;                        // 0..83
    const int it = bxp >> 2, i4 = bxp & 3;           // it 0..20
    const int yb = blockIdx.y & 1;
    const int ntile = blockIdx.y >> 1;               // 0..31
    const int r = (t >> 3) + 32 * i4 + 128 * yb;     // row in tile, 0..255
    const int c = (slot - r) & 7;
    const int k0 = it * 64 + c * 8;
    const int n = ntile * BN + r;
#pragma unroll
    for (int e = 0; e < 8; e++) {
      const int k = k0 + e;
      float v = 0.f;
      if (k < KRAW) {
        const int y = k / LXC;
        const int x = k - y * LXC;
        v = Wy[n * LYC + y] * Wx[n * LXC + x] * 256.f;
      }
      h[e] = (_Float16)v;
    }
    // staged position p = r*8 + slot = yb*1024 + i4*256 + t
    *(half8*)(B + (size_t)ntile * B_TILE_H + (size_t)it * A_IT_H +
              (size_t)(yb * 1024 + i4 * 256 + t) * 8) = h;
  }
}

// Fused GEMM, counted-vmcnt double-buffered pipeline (T3/T4/T5):
// block tile 256(M)x256(N), BK=64, 8 waves (2M x 4N) each 128x64 using
// 32x32x16 f16 MFMA (acc 8 x f32x16 = 128 AGPR). LDS 128 KB (2 buffers).
// Steady state: issue 8 global_load_lds for tile t+1, s_waitcnt vmcnt(8)
// (waits only tile t's loads; never drains to 0), s_barrier, compute,
// s_barrier. Epilogue contracts 64 channels with Wc, adds bias, ELU.
__global__ __launch_bounds__(512, 2) void gemm_fused_kernel(
    const _Float16* __restrict__ A, const _Float16* __restrict__ B,
    const float* __restrict__ Wc, const float* __restrict__ bias,
    float* __restrict__ out) {
  __shared__ _Float16 As[2][BM * BK];  // 2 x 32 KB
  __shared__ _Float16 Bs[2][BN * BK];  // 2 x 32 KB

  // Bijective XCD swizzle (2048 % 8 == 0): each XCD gets 256 consecutive
  // gids = 8 mtiles x 32 ntiles; per-K-step working set 1.25 MB -> L2.
  const int bid = blockIdx.x;              // 0..2047
  const int gid = (bid & 7) * 256 + (bid >> 3);
  const int mtile = gid >> 5;              // 0..63
  const int ntile = gid & 31;              // 0..31
  const int tileN = ntile * BN;

  const int t = threadIdx.x;
  const int lane = t & 63;
  const int wave = t >> 6;
  const int wm = wave >> 2, wn = wave & 3;  // 2x4 waves; wave tile 128x64
  const int r32 = lane & 31, hh = lane >> 5;

  f32x16 acc[4][2] = {};  // [mb][nb], mb: 4x32 rows, nb: 2x32 cols

  const _Float16* pA = A + (size_t)mtile * A_TILE_H + t * 8;
  const _Float16* pB = B + (size_t)ntile * B_TILE_H + t * 8;

  auto stage = [&](int b, int it) {
    const _Float16* sA = pA + it * A_IT_H;
    const _Float16* sB = pB + it * A_IT_H;
    _Float16* lA = &As[b][t * 8];
    _Float16* lB = &Bs[b][t * 8];
#pragma unroll
    for (int i = 0; i < 4; i++) async_copy16(sA + i * 4096, lA + i * 4096);
#pragma unroll
    for (int i = 0; i < 4; i++) async_copy16(sB + i * 4096, lB + i * 4096);
  };

  auto compute = [&](int b) {
#pragma unroll
    for (int ks = 0; ks < 4; ks++) {
      const int cc = 2 * ks + hh;  // source chunk for this k-substep
      half8 bf[2];
#pragma unroll
      for (int nb = 0; nb < 2; nb++) {
        const int r = wn * 64 + nb * 32 + r32;
        bf[nb] = *(const half8*)(&Bs[b][r * 64 + ((cc + r) & 7) * 8]);
      }
      __builtin_amdgcn_s_setprio(1);
#pragma unroll
      for (int mb = 0; mb < 4; mb++) {
        const int r = wm * 128 + mb * 32 + r32;
        const half8 af = *(const half8*)(&As[b][r * 64 + ((cc + r) & 7) * 8]);
#pragma unroll
        for (int nb = 0; nb < 2; nb++)
          acc[mb][nb] = __builtin_amdgcn_mfma_f32_32x32x16_f16(
              af, bf[nb], acc[mb][nb], 0, 0, 0);
      }
      __builtin_amdgcn_s_setprio(0);
    }
  };

  stage(0, 0);
#pragma unroll 1
  for (int it = 0; it < KITER - 1; ++it) {
    stage((it + 1) & 1, it + 1);                  // prefetch next K-tile
    asm volatile("s_waitcnt vmcnt(8)" ::: "memory");  // tile it's loads done
    __builtin_amdgcn_s_barrier();                 // buf[it&1] visible to all
    compute(it & 1);
    __builtin_amdgcn_s_barrier();                 // all reads of buf[it&1] done
  }
  asm volatile("s_waitcnt vmcnt(0)" ::: "memory");
  __builtin_amdgcn_s_barrier();
  compute((KITER - 1) & 1);

  // Epilogue. C/D layout (32x32): col = lane&31, row = (reg&3)+8*(reg>>2)+4*hh.
  // Wave rows = 128 = 2 images x 64 channels; mb pairs (0,1)->img0, (2,3)->img1;
  // channel = (mb&1)*32 + row.
  const int ibase = mtile * 4 + wm * 2;
  float v[2][2];  // [img][nb]
#pragma unroll
  for (int nb = 0; nb < 2; nb++) {
    const int n_g = tileN + wn * 64 + nb * 32 + r32;
    const float* wc = Wc + (size_t)n_g * NCONV;
    f32x4 w[2][4];
#pragma unroll
    for (int hf = 0; hf < 2; hf++)
#pragma unroll
      for (int g = 0; g < 4; g++)
        w[hf][g] = *(const f32x4*)(wc + hf * 32 + hh * 4 + g * 8);
#pragma unroll
    for (int img = 0; img < 2; img++) {
      float p = 0.f;
#pragma unroll
      for (int hf = 0; hf < 2; hf++)
#pragma unroll
        for (int g = 0; g < 4; g++)
#pragma unroll
          for (int q = 0; q < 4; q++)
            p += acc[img * 2 + hf][nb][g * 4 + q] * w[hf][g][q];
      p += __shfl_xor(p, 32);
      v[img][nb] = p;
    }
  }
  // Each lane writes image hh (its half), both nb; values identical per half.
  const int img = ibase + hh;
#pragma unroll
  for (int nb = 0; nb < 2; nb++) {
    const int n_out = tileN + wn * 64 + nb * 32 + r32;
    float z = v[hh][nb] * 0.00390625f + bias[n_out];  // undo x256 scaling
    z = z > 0.f ? z : (__expf(z) - 1.f);
    out[(size_t)img * NNEUR + n_out] = z;
  }
}

extern "C" void kernel_launch(void* const* d_in, const int* in_sizes, int n_in,
                              void* d_out, int out_size, void* d_ws,
                              size_t ws_size, hipStream_t stream) {
  const float* conv = (const float*)d_in[0];
  const float* Wc = (const float*)d_in[1];
  const float* Wy = (const float*)d_in[2];
  const float* Wx = (const float*)d_in[3];
  const float* bias = (const float*)d_in[4];
  float* out = (float*)d_out;

  _Float16* Abuf = (_Float16*)d_ws;                                      // 44.0 MB
  _Float16* Bbuf = (_Float16*)((char*)d_ws + (size_t)MROWS * KPAD * 2);  // 22.0 MB

  prep_kernel<<<dim3(252, 64), 256, 0, stream>>>(conv, Wy, Wx, Abuf, Bbuf);
  gemm_fused_kernel<<<2048, 512, 0, stream>>>(Abuf, Bbuf, Wc, bias, out);
}